// Round 3
// baseline (636.279 us; speedup 1.0000x reference)
//
#include <hip/hip_runtime.h>

#define N_NODES 50000
#define N_EDGES 800000
#define N_GRAPHS 50
#define D 128
#define D_OUT 10

// Swizzled float4-group index for 64x128 LDS tiles stored as [row][32 groups]:
// group g of row goes to slot g ^ ((row>>2)&15).  Makes gather-writes, A-reads
// (16-lane broadcast x 4 consecutive rows) and W-reads (16 col-groups) all
// <=2-way bank-aliased (free per m136).
#define SWZ(row, g) ((g) ^ (((row) >> 2) & 15))

// ---------------------------------------------------------------------------
// 1) Degree histograms
// ---------------------------------------------------------------------------
__global__ __launch_bounds__(256) void hist_edges(const int* __restrict__ src,
                                                  const int* __restrict__ dst,
                                                  int* __restrict__ cnt_dst,
                                                  int* __restrict__ cnt_src) {
    int i = blockIdx.x * 256 + threadIdx.x;
    if (i < N_EDGES) {
        atomicAdd(&cnt_dst[dst[i]], 1);
        atomicAdd(&cnt_src[src[i]], 1);
    }
}

// ---------------------------------------------------------------------------
// 2) Single-block scan: cnt -> row_ptr; rewrites cnt in-place as scatter cursor
// ---------------------------------------------------------------------------
__global__ __launch_bounds__(1024) void scan_k(int* __restrict__ cnt,
                                               int* __restrict__ row_ptr) {
    __shared__ int wsum[16];
    __shared__ int carry_s;
    int tid = threadIdx.x;
    int lane = tid & 63, wid = tid >> 6;
    if (tid == 0) carry_s = 0;
    __syncthreads();
    for (int base = 0; base < N_NODES; base += 4096) {
        int i0 = base + tid * 4;
        int v0 = (i0 + 0 < N_NODES) ? cnt[i0 + 0] : 0;
        int v1 = (i0 + 1 < N_NODES) ? cnt[i0 + 1] : 0;
        int v2 = (i0 + 2 < N_NODES) ? cnt[i0 + 2] : 0;
        int v3 = (i0 + 3 < N_NODES) ? cnt[i0 + 3] : 0;
        int s = v0 + v1 + v2 + v3;
        int x = s;
        #pragma unroll
        for (int d = 1; d < 64; d <<= 1) {
            int y = __shfl_up(x, d, 64);
            if (lane >= d) x += y;
        }
        if (lane == 63) wsum[wid] = x;
        __syncthreads();
        if (wid == 0) {
            int t = (lane < 16) ? wsum[lane] : 0;
            #pragma unroll
            for (int d = 1; d < 16; d <<= 1) {
                int y = __shfl_up(t, d, 64);
                if (lane >= d) t += y;
            }
            if (lane < 16) wsum[lane] = t;
        }
        __syncthreads();
        int woff = (wid == 0) ? 0 : wsum[wid - 1];
        int excl = carry_s + woff + (x - s);
        int run = excl;
        if (i0 + 0 < N_NODES) { row_ptr[i0 + 0] = run; cnt[i0 + 0] = run; } run += v0;
        if (i0 + 1 < N_NODES) { row_ptr[i0 + 1] = run; cnt[i0 + 1] = run; } run += v1;
        if (i0 + 2 < N_NODES) { row_ptr[i0 + 2] = run; cnt[i0 + 2] = run; } run += v2;
        if (i0 + 3 < N_NODES) { row_ptr[i0 + 3] = run; cnt[i0 + 3] = run; } run += v3;
        __syncthreads();
        if (tid == 0) carry_s += wsum[15];
        __syncthreads();
    }
    if (tid == 0) row_ptr[N_NODES] = carry_s;
}

// ---------------------------------------------------------------------------
// 3) Norms
// ---------------------------------------------------------------------------
__global__ __launch_bounds__(256) void norms_k(const int* __restrict__ cnt_src,
                                               const int* __restrict__ row_ptr,
                                               float* __restrict__ ns,
                                               float* __restrict__ nd) {
    int v = blockIdx.x * 256 + threadIdx.x;
    if (v < N_NODES) {
        int od = cnt_src[v];
        int id = row_ptr[v + 1] - row_ptr[v];
        ns[v] = 1.0f / sqrtf((float)(od > 1 ? od : 1));
        nd[v] = 1.0f / sqrtf((float)(id > 1 ? id : 1));
    }
}

// ---------------------------------------------------------------------------
// 4) CSR scatter (no weights: ns is folded into the gathered features)
// ---------------------------------------------------------------------------
__global__ __launch_bounds__(256) void scatter_k(const int* __restrict__ src,
                                                 const int* __restrict__ dst,
                                                 int* __restrict__ fill,
                                                 int* __restrict__ col) {
    int i = blockIdx.x * 256 + threadIdx.x;
    if (i < N_EDGES) {
        int s = src[i];
        int p = atomicAdd(&fill[dst[i]], 1);
        col[p] = s;
    }
}

// ---------------------------------------------------------------------------
// 5) Pre-scale: out[v,:] = ns[v] * x[v,:]   (so layer-1 gather is unweighted)
// ---------------------------------------------------------------------------
__global__ __launch_bounds__(256) void scale_k(const float* __restrict__ x,
                                               const float* __restrict__ ns,
                                               float* __restrict__ out) {
    int idx = blockIdx.x * 256 + threadIdx.x;      // float4 index
    if (idx < N_NODES * 32) {
        float4 v = ((const float4*)x)[idx];
        float s = ns[idx >> 5];
        ((float4*)out)[idx] = make_float4(v.x * s, v.y * s, v.z * s, v.w * s);
    }
}

// ---------------------------------------------------------------------------
// 6) Fused layer: Z[row0..row0+63] = relu( nd ∘ (A · x) @ W + b ) [∘ ns]
//    x is pre-scaled by ns.  Gather -> LDS Agg (swizzled) -> inner-product
//    GEMM vs swizzle-transposed W half -> fused epilogue.  LDS = 64 KB,
//    2 blocks/CU; GEMM VALU hides under gather VMEM.
// ---------------------------------------------------------------------------
template <bool SCALE_OUT>
__global__ __launch_bounds__(256, 2) void fused_layer_k(
        const float* __restrict__ x,
        const int* __restrict__ row_ptr,
        const int* __restrict__ col,
        const float* __restrict__ ns,
        const float* __restrict__ nd,
        const float* __restrict__ W,
        const float* __restrict__ bias,
        float* __restrict__ out) {
    __shared__ float Agg[64 * 128];   // [r][g] swizzled, 32 KB
    __shared__ float Wt[64 * 128];    // [c][g] swizzled (one 64-col half), 32 KB
    int tid = threadIdx.x;
    int row0 = blockIdx.x * 64;
    int lane = tid & 31;
    const float4* x4 = (const float4*)x;

    // ---- gather: 8 nodes per pass (32 lanes x float4 each), 8 passes
    for (int pass = 0; pass < 8; pass++) {
        int r = pass * 8 + (tid >> 5);
        int node = row0 + r;
        float4 a0 = make_float4(0.f, 0.f, 0.f, 0.f);
        float4 a1 = make_float4(0.f, 0.f, 0.f, 0.f);
        if (node < N_NODES) {
            int s = row_ptr[node];
            int e = row_ptr[node + 1];
            int i = s;
            for (; i + 8 <= e; i += 8) {
                int c0 = col[i + 0], c1 = col[i + 1], c2 = col[i + 2], c3 = col[i + 3];
                int c4 = col[i + 4], c5 = col[i + 5], c6 = col[i + 6], c7 = col[i + 7];
                float4 h0 = x4[c0 * 32 + lane];
                float4 h1 = x4[c1 * 32 + lane];
                float4 h2 = x4[c2 * 32 + lane];
                float4 h3 = x4[c3 * 32 + lane];
                float4 h4 = x4[c4 * 32 + lane];
                float4 h5 = x4[c5 * 32 + lane];
                float4 h6 = x4[c6 * 32 + lane];
                float4 h7 = x4[c7 * 32 + lane];
                a0.x += h0.x + h2.x; a0.y += h0.y + h2.y; a0.z += h0.z + h2.z; a0.w += h0.w + h2.w;
                a1.x += h1.x + h3.x; a1.y += h1.y + h3.y; a1.z += h1.z + h3.z; a1.w += h1.w + h3.w;
                a0.x += h4.x + h6.x; a0.y += h4.y + h6.y; a0.z += h4.z + h6.z; a0.w += h4.w + h6.w;
                a1.x += h5.x + h7.x; a1.y += h5.y + h7.y; a1.z += h5.z + h7.z; a1.w += h5.w + h7.w;
            }
            for (; i < e; i++) {
                float4 hv = x4[col[i] * 32 + lane];
                a0.x += hv.x; a0.y += hv.y; a0.z += hv.z; a0.w += hv.w;
            }
            float ndv = nd[node];
            a0.x = (a0.x + a1.x) * ndv;
            a0.y = (a0.y + a1.y) * ndv;
            a0.z = (a0.z + a1.z) * ndv;
            a0.w = (a0.w + a1.w) * ndv;
        }
        ((float4*)Agg)[r * 32 + SWZ(r, lane)] = a0;
    }

    // ---- GEMM: 4x4 micro-tile, two 64-col halves of W
    int cg = tid & 15;     // col group (c0 = cg*4 within half)
    int rg = tid >> 4;     // row group (r0 = rg*4)
    float acc[2][4][4];
    #pragma unroll
    for (int h = 0; h < 2; h++)
        #pragma unroll
        for (int i = 0; i < 4; i++)
            #pragma unroll
            for (int j = 0; j < 4; j++) acc[h][i][j] = 0.f;

    for (int h = 0; h < 2; h++) {
        __syncthreads();   // Agg complete (h=0) / Wt reads of prev half done (h=1)
        #pragma unroll
        for (int it = 0; it < 8; it++) {
            int linear = it * 256 + tid;       // 2048 = 128 k x 16 col-groups
            int k = linear >> 4;
            int cl = linear & 15;
            float4 w = ((const float4*)(W + k * 128 + h * 64))[cl];
            int g = k >> 2, kb = k & 3;
            Wt[(cl * 4 + 0) * 128 + SWZ(cl * 4 + 0, g) * 4 + kb] = w.x;
            Wt[(cl * 4 + 1) * 128 + SWZ(cl * 4 + 1, g) * 4 + kb] = w.y;
            Wt[(cl * 4 + 2) * 128 + SWZ(cl * 4 + 2, g) * 4 + kb] = w.z;
            Wt[(cl * 4 + 3) * 128 + SWZ(cl * 4 + 3, g) * 4 + kb] = w.w;
        }
        __syncthreads();
        for (int g = 0; g < 32; g++) {
            float4 av[4], wv[4];
            #pragma unroll
            for (int i = 0; i < 4; i++)
                av[i] = ((const float4*)Agg)[(rg * 4 + i) * 32 + SWZ(rg * 4 + i, g)];
            #pragma unroll
            for (int j = 0; j < 4; j++)
                wv[j] = ((const float4*)Wt)[(cg * 4 + j) * 32 + SWZ(cg * 4 + j, g)];
            #pragma unroll
            for (int i = 0; i < 4; i++)
                #pragma unroll
                for (int j = 0; j < 4; j++) {
                    acc[h][i][j] = fmaf(av[i].x, wv[j].x, acc[h][i][j]);
                    acc[h][i][j] = fmaf(av[i].y, wv[j].y, acc[h][i][j]);
                    acc[h][i][j] = fmaf(av[i].z, wv[j].z, acc[h][i][j]);
                    acc[h][i][j] = fmaf(av[i].w, wv[j].w, acc[h][i][j]);
                }
        }
    }

    // ---- epilogue: bias + relu (+ ns pre-scale for the next layer's gather)
    #pragma unroll
    for (int h = 0; h < 2; h++) {
        float4 bv = ((const float4*)bias)[h * 16 + cg];
        #pragma unroll
        for (int i = 0; i < 4; i++) {
            int row = row0 + rg * 4 + i;
            if (row < N_NODES) {
                float4 o;
                o.x = fmaxf(acc[h][i][0] + bv.x, 0.f);
                o.y = fmaxf(acc[h][i][1] + bv.y, 0.f);
                o.z = fmaxf(acc[h][i][2] + bv.z, 0.f);
                o.w = fmaxf(acc[h][i][3] + bv.w, 0.f);
                if (SCALE_OUT) {
                    float s = ns[row];
                    o.x *= s; o.y *= s; o.z *= s; o.w *= s;
                }
                ((float4*)out)[row * 32 + h * 16 + cg] = o;
            }
        }
    }
}

// ---------------------------------------------------------------------------
// 7) Fused projection + readout (segmented wave-scan over sorted graph_ids)
// ---------------------------------------------------------------------------
__global__ __launch_bounds__(256) void proj_readout_k(const float* __restrict__ h,
                                                      const int* __restrict__ gid,
                                                      const float* __restrict__ Wm,
                                                      float* __restrict__ hgp,
                                                      int* __restrict__ gcnt) {
    __shared__ float Wmt[10 * 144];
    int tid = threadIdx.x;
    for (int i = tid; i < 1280; i += 256) {
        int k = i / 10, o = i % 10;
        Wmt[o * 144 + k + 4 * (k >> 5)] = Wm[i];
    }
    __syncthreads();

    int v = blockIdx.x * 64 + (tid >> 2);
    int quarter = tid & 3;
    int lane = tid & 63;

    float acc[D_OUT];
    #pragma unroll
    for (int o = 0; o < D_OUT; o++) acc[o] = 0.f;
    int g = -1;
    int cnt = 0;
    if (v < N_NODES) {
        g = gid[v];
        cnt = (quarter == 0) ? 1 : 0;
        const float4* h4 = (const float4*)h + v * 32 + quarter * 8;
        const float* wbase = Wmt + quarter * 36;
        #pragma unroll
        for (int kk = 0; kk < 8; kk++) {
            float4 hv = h4[kk];
            #pragma unroll
            for (int o = 0; o < D_OUT; o++) {
                float4 w = *(const float4*)(wbase + o * 144 + kk * 4);
                acc[o] += hv.x * w.x + hv.y * w.y + hv.z * w.z + hv.w * w.w;
            }
        }
    }

    #pragma unroll
    for (int d = 1; d < 64; d <<= 1) {
        int gp = __shfl_up(g, d, 64);
        int cp = __shfl_up(cnt, d, 64);
        bool take = (lane >= d) && (gp == g);
        #pragma unroll
        for (int o = 0; o < D_OUT; o++) {
            float ap = __shfl_up(acc[o], d, 64);
            if (take) acc[o] += ap;
        }
        if (take) cnt += cp;
    }
    int gn = __shfl_down(g, 1, 64);
    bool tail = (lane == 63) || (gn != g);
    if (tail && g >= 0) {
        #pragma unroll
        for (int o = 0; o < D_OUT; o++) atomicAdd(&hgp[g * D_OUT + o], acc[o]);
        if (cnt > 0) atomicAdd(&gcnt[g], cnt);
    }
}

// ---------------------------------------------------------------------------
// 8) Final: logits = hgp/cnt + bm ; log_softmax over axis 0 (graphs)
// ---------------------------------------------------------------------------
__global__ __launch_bounds__(512) void final_k(const float* __restrict__ hgp,
                                               const int* __restrict__ gcnt,
                                               const float* __restrict__ bm,
                                               float* __restrict__ out) {
    __shared__ float lg[N_GRAPHS * D_OUT];
    __shared__ float colm[D_OUT], colls[D_OUT];
    int tid = threadIdx.x;
    if (tid < N_GRAPHS * D_OUT) {
        int g = tid / D_OUT, o = tid % D_OUT;
        float c = (float)gcnt[g];
        lg[tid] = hgp[tid] / (c > 1.f ? c : 1.f) + bm[o];
    }
    __syncthreads();
    if (tid < D_OUT) {
        float m = -1e30f;
        for (int g = 0; g < N_GRAPHS; g++) m = fmaxf(m, lg[g * D_OUT + tid]);
        float s = 0.f;
        for (int g = 0; g < N_GRAPHS; g++) s += expf(lg[g * D_OUT + tid] - m);
        colm[tid] = m; colls[tid] = logf(s);
    }
    __syncthreads();
    if (tid < N_GRAPHS * D_OUT) {
        int o = tid % D_OUT;
        out[tid] = lg[tid] - colm[o] - colls[o];
    }
}

// ---------------------------------------------------------------------------
// Launch
// ---------------------------------------------------------------------------
extern "C" void kernel_launch(void* const* d_in, const int* in_sizes, int n_in,
                              void* d_out, int out_size, void* d_ws, size_t ws_size,
                              hipStream_t stream) {
    const float* h_in = (const float*)d_in[0];
    const int*   src  = (const int*)d_in[1];
    const int*   dst  = (const int*)d_in[2];
    const int*   gid  = (const int*)d_in[3];
    const float* W1 = (const float*)d_in[4];  const float* b1 = (const float*)d_in[5];
    const float* W2 = (const float*)d_in[6];  const float* b2 = (const float*)d_in[7];
    const float* W3 = (const float*)d_in[8];  const float* b3 = (const float*)d_in[9];
    const float* Wm = (const float*)d_in[10]; const float* bm = (const float*)d_in[11];

    char* ws = (char*)d_ws;
    int*   cnt     = (int*)(ws + 0);          // 50000 ints; becomes scatter cursor
    int*   cnt_src = (int*)(ws + 200000);     // 50000 ints
    int*   gcnt    = (int*)(ws + 400000);     // 64 ints
    float* hgp     = (float*)(ws + 400256);   // 512 floats
    // zero region = [0, 402304)
    int*   row_ptr = (int*)(ws + 402304);     // 50001 ints (pad 50004)
    int*   col     = (int*)(ws + 602320);     // 800000 ints
    float* ns      = (float*)(ws + 3802320);  // 50000 floats
    float* nd      = (float*)(ws + 4002320);  // 50000 floats
    float* buf0    = (float*)(ws + 4202320);  // 6.4M floats
    float* buf1    = (float*)(ws + 29802320); // 6.4M floats
    // total: 55,402,320 bytes

    hipMemsetAsync(ws, 0, 402304, stream);

    hist_edges<<<3125, 256, 0, stream>>>(src, dst, cnt, cnt_src);
    scan_k<<<1, 1024, 0, stream>>>(cnt, row_ptr);
    norms_k<<<196, 256, 0, stream>>>(cnt_src, row_ptr, ns, nd);
    scatter_k<<<3125, 256, 0, stream>>>(src, dst, cnt, col);
    scale_k<<<6250, 256, 0, stream>>>(h_in, ns, buf1);   // buf1 = ns ∘ h

    // L1: buf1 -> buf0 (epilogue pre-scales by ns for L2's gather)
    fused_layer_k<true ><<<782, 256, 0, stream>>>(buf1, row_ptr, col, ns, nd, W1, b1, buf0);
    // L2: buf0 -> buf1 (pre-scaled for L3)
    fused_layer_k<true ><<<782, 256, 0, stream>>>(buf0, row_ptr, col, ns, nd, W2, b2, buf1);
    // L3: buf1 -> buf0 (unscaled output for readout)
    fused_layer_k<false><<<782, 256, 0, stream>>>(buf1, row_ptr, col, ns, nd, W3, b3, buf0);

    proj_readout_k<<<782, 256, 0, stream>>>(buf0, gid, Wm, hgp, gcnt);
    final_k<<<1, 512, 0, stream>>>(hgp, gcnt, bm, (float*)d_out);
}

// Round 4
// 582.101 us; speedup vs baseline: 1.0931x; 1.0931x over previous
//
#include <hip/hip_runtime.h>

#define N_NODES 50000
#define N_EDGES 800000
#define N_GRAPHS 50
#define D 128
#define D_OUT 10

// Swizzled float4-group index for 64x128 LDS tile stored as [row][32 groups]:
// group g of row r lives at slot g ^ ((r>>2)&15).  Gather-writes (row-major
// b128) and GEMM reads (4 row-groups x 16-lane broadcast) are conflict-free
// or 2-way (free per m136).
#define SWZ(row, g) ((g) ^ (((row) >> 2) & 15))

// ---------------------------------------------------------------------------
// 1) Degree histograms
// ---------------------------------------------------------------------------
__global__ __launch_bounds__(256) void hist_edges(const int* __restrict__ src,
                                                  const int* __restrict__ dst,
                                                  int* __restrict__ cnt_dst,
                                                  int* __restrict__ cnt_src) {
    int i = blockIdx.x * 256 + threadIdx.x;
    if (i < N_EDGES) {
        atomicAdd(&cnt_dst[dst[i]], 1);
        atomicAdd(&cnt_src[src[i]], 1);
    }
}

// ---------------------------------------------------------------------------
// 2) Single-block scan: cnt -> row_ptr; rewrites cnt in-place as scatter cursor
// ---------------------------------------------------------------------------
__global__ __launch_bounds__(1024) void scan_k(int* __restrict__ cnt,
                                               int* __restrict__ row_ptr) {
    __shared__ int wsum[16];
    __shared__ int carry_s;
    int tid = threadIdx.x;
    int lane = tid & 63, wid = tid >> 6;
    if (tid == 0) carry_s = 0;
    __syncthreads();
    for (int base = 0; base < N_NODES; base += 4096) {
        int i0 = base + tid * 4;
        int v0 = (i0 + 0 < N_NODES) ? cnt[i0 + 0] : 0;
        int v1 = (i0 + 1 < N_NODES) ? cnt[i0 + 1] : 0;
        int v2 = (i0 + 2 < N_NODES) ? cnt[i0 + 2] : 0;
        int v3 = (i0 + 3 < N_NODES) ? cnt[i0 + 3] : 0;
        int s = v0 + v1 + v2 + v3;
        int x = s;
        #pragma unroll
        for (int d = 1; d < 64; d <<= 1) {
            int y = __shfl_up(x, d, 64);
            if (lane >= d) x += y;
        }
        if (lane == 63) wsum[wid] = x;
        __syncthreads();
        if (wid == 0) {
            int t = (lane < 16) ? wsum[lane] : 0;
            #pragma unroll
            for (int d = 1; d < 16; d <<= 1) {
                int y = __shfl_up(t, d, 64);
                if (lane >= d) t += y;
            }
            if (lane < 16) wsum[lane] = t;
        }
        __syncthreads();
        int woff = (wid == 0) ? 0 : wsum[wid - 1];
        int excl = carry_s + woff + (x - s);
        int run = excl;
        if (i0 + 0 < N_NODES) { row_ptr[i0 + 0] = run; cnt[i0 + 0] = run; } run += v0;
        if (i0 + 1 < N_NODES) { row_ptr[i0 + 1] = run; cnt[i0 + 1] = run; } run += v1;
        if (i0 + 2 < N_NODES) { row_ptr[i0 + 2] = run; cnt[i0 + 2] = run; } run += v2;
        if (i0 + 3 < N_NODES) { row_ptr[i0 + 3] = run; cnt[i0 + 3] = run; } run += v3;
        __syncthreads();
        if (tid == 0) carry_s += wsum[15];
        __syncthreads();
    }
    if (tid == 0) row_ptr[N_NODES] = carry_s;
}

// ---------------------------------------------------------------------------
// 3) Norms
// ---------------------------------------------------------------------------
__global__ __launch_bounds__(256) void norms_k(const int* __restrict__ cnt_src,
                                               const int* __restrict__ row_ptr,
                                               float* __restrict__ ns,
                                               float* __restrict__ nd) {
    int v = blockIdx.x * 256 + threadIdx.x;
    if (v < N_NODES) {
        int od = cnt_src[v];
        int id = row_ptr[v + 1] - row_ptr[v];
        ns[v] = 1.0f / sqrtf((float)(od > 1 ? od : 1));
        nd[v] = 1.0f / sqrtf((float)(id > 1 ? id : 1));
    }
}

// ---------------------------------------------------------------------------
// 4) CSR scatter
// ---------------------------------------------------------------------------
__global__ __launch_bounds__(256) void scatter_k(const int* __restrict__ src,
                                                 const int* __restrict__ dst,
                                                 int* __restrict__ fill,
                                                 int* __restrict__ col) {
    int i = blockIdx.x * 256 + threadIdx.x;
    if (i < N_EDGES) {
        int s = src[i];
        int p = atomicAdd(&fill[dst[i]], 1);
        col[p] = s;
    }
}

// ---------------------------------------------------------------------------
// 5) Pre-scale: out[v,:] = ns[v] * x[v,:]   (layer-1 gather is then unweighted)
// ---------------------------------------------------------------------------
__global__ __launch_bounds__(256) void scale_k(const float* __restrict__ x,
                                               const float* __restrict__ ns,
                                               float* __restrict__ out) {
    int idx = blockIdx.x * 256 + threadIdx.x;
    if (idx < N_NODES * 32) {
        float4 v = ((const float4*)x)[idx];
        float s = ns[idx >> 5];
        ((float4*)out)[idx] = make_float4(v.x * s, v.y * s, v.z * s, v.w * s);
    }
}

// ---------------------------------------------------------------------------
// 6) Fused layer (occupancy-fixed): LDS = Agg only (32 KB) -> 5 blocks/CU,
//    20 waves/CU.  W read from global in the GEMM (16-lane broadcast per
//    instruction, L1/L2-hot).  Gather: unroll 8, 4 chains.
// ---------------------------------------------------------------------------
template <bool SCALE_OUT>
__global__ __launch_bounds__(256, 5) void fused_layer_k(
        const float* __restrict__ x,
        const int* __restrict__ row_ptr,
        const int* __restrict__ col,
        const float* __restrict__ ns,
        const float* __restrict__ nd,
        const float* __restrict__ W,
        const float* __restrict__ bias,
        float* __restrict__ out) {
    __shared__ float Agg[64 * 128];   // [r][g] swizzled, 32 KB
    int tid = threadIdx.x;
    int row0 = blockIdx.x * 64;
    int lane = tid & 31;
    const float4* x4 = (const float4*)x;

    // ---- gather: 8 nodes per pass (32 lanes x float4), 8 passes
    for (int pass = 0; pass < 8; pass++) {
        int r = pass * 8 + (tid >> 5);
        int node = row0 + r;
        float4 a0 = make_float4(0.f, 0.f, 0.f, 0.f);
        float4 a1 = make_float4(0.f, 0.f, 0.f, 0.f);
        float4 a2 = make_float4(0.f, 0.f, 0.f, 0.f);
        float4 a3 = make_float4(0.f, 0.f, 0.f, 0.f);
        if (node < N_NODES) {
            int s = row_ptr[node];
            int e = row_ptr[node + 1];
            int i = s;
            for (; i + 8 <= e; i += 8) {
                int c0 = col[i + 0], c1 = col[i + 1], c2 = col[i + 2], c3 = col[i + 3];
                int c4 = col[i + 4], c5 = col[i + 5], c6 = col[i + 6], c7 = col[i + 7];
                float4 h0 = x4[c0 * 32 + lane];
                float4 h1 = x4[c1 * 32 + lane];
                float4 h2 = x4[c2 * 32 + lane];
                float4 h3 = x4[c3 * 32 + lane];
                float4 h4 = x4[c4 * 32 + lane];
                float4 h5 = x4[c5 * 32 + lane];
                float4 h6 = x4[c6 * 32 + lane];
                float4 h7 = x4[c7 * 32 + lane];
                a0.x += h0.x + h4.x; a0.y += h0.y + h4.y; a0.z += h0.z + h4.z; a0.w += h0.w + h4.w;
                a1.x += h1.x + h5.x; a1.y += h1.y + h5.y; a1.z += h1.z + h5.z; a1.w += h1.w + h5.w;
                a2.x += h2.x + h6.x; a2.y += h2.y + h6.y; a2.z += h2.z + h6.z; a2.w += h2.w + h6.w;
                a3.x += h3.x + h7.x; a3.y += h3.y + h7.y; a3.z += h3.z + h7.z; a3.w += h3.w + h7.w;
            }
            for (; i < e; i++) {
                float4 hv = x4[col[i] * 32 + lane];
                a0.x += hv.x; a0.y += hv.y; a0.z += hv.z; a0.w += hv.w;
            }
            float ndv = nd[node];
            a0.x = (a0.x + a1.x + a2.x + a3.x) * ndv;
            a0.y = (a0.y + a1.y + a2.y + a3.y) * ndv;
            a0.z = (a0.z + a1.z + a2.z + a3.z) * ndv;
            a0.w = (a0.w + a1.w + a2.w + a3.w) * ndv;
        }
        ((float4*)Agg)[r * 32 + SWZ(r, lane)] = a0;
    }
    __syncthreads();

    // ---- GEMM: micro-tile 4 rows x 8 cols, W from global (broadcast loads)
    int cg = tid & 15;     // cols cg*8 .. cg*8+7
    int rg = tid >> 4;     // rows rg*4 .. rg*4+3
    float acc[4][8];
    #pragma unroll
    for (int i = 0; i < 4; i++)
        #pragma unroll
        for (int j = 0; j < 8; j++) acc[i][j] = 0.f;

    const float* Wc = W + cg * 8;
    for (int g = 0; g < 32; g++) {
        float4 av[4];
        #pragma unroll
        for (int i = 0; i < 4; i++)
            av[i] = ((const float4*)Agg)[(rg * 4 + i) * 32 + SWZ(rg * 4 + i, g)];
        #pragma unroll
        for (int kb = 0; kb < 4; kb++) {
            int k = g * 4 + kb;
            float4 w0 = *(const float4*)(Wc + k * 128);
            float4 w1 = *(const float4*)(Wc + k * 128 + 4);
            float a0 = ((const float*)&av[0])[kb];
            float a1 = ((const float*)&av[1])[kb];
            float a2 = ((const float*)&av[2])[kb];
            float a3 = ((const float*)&av[3])[kb];
            acc[0][0] = fmaf(a0, w0.x, acc[0][0]); acc[0][1] = fmaf(a0, w0.y, acc[0][1]);
            acc[0][2] = fmaf(a0, w0.z, acc[0][2]); acc[0][3] = fmaf(a0, w0.w, acc[0][3]);
            acc[0][4] = fmaf(a0, w1.x, acc[0][4]); acc[0][5] = fmaf(a0, w1.y, acc[0][5]);
            acc[0][6] = fmaf(a0, w1.z, acc[0][6]); acc[0][7] = fmaf(a0, w1.w, acc[0][7]);
            acc[1][0] = fmaf(a1, w0.x, acc[1][0]); acc[1][1] = fmaf(a1, w0.y, acc[1][1]);
            acc[1][2] = fmaf(a1, w0.z, acc[1][2]); acc[1][3] = fmaf(a1, w0.w, acc[1][3]);
            acc[1][4] = fmaf(a1, w1.x, acc[1][4]); acc[1][5] = fmaf(a1, w1.y, acc[1][5]);
            acc[1][6] = fmaf(a1, w1.z, acc[1][6]); acc[1][7] = fmaf(a1, w1.w, acc[1][7]);
            acc[2][0] = fmaf(a2, w0.x, acc[2][0]); acc[2][1] = fmaf(a2, w0.y, acc[2][1]);
            acc[2][2] = fmaf(a2, w0.z, acc[2][2]); acc[2][3] = fmaf(a2, w0.w, acc[2][3]);
            acc[2][4] = fmaf(a2, w1.x, acc[2][4]); acc[2][5] = fmaf(a2, w1.y, acc[2][5]);
            acc[2][6] = fmaf(a2, w1.z, acc[2][6]); acc[2][7] = fmaf(a2, w1.w, acc[2][7]);
            acc[3][0] = fmaf(a3, w0.x, acc[3][0]); acc[3][1] = fmaf(a3, w0.y, acc[3][1]);
            acc[3][2] = fmaf(a3, w0.z, acc[3][2]); acc[3][3] = fmaf(a3, w0.w, acc[3][3]);
            acc[3][4] = fmaf(a3, w1.x, acc[3][4]); acc[3][5] = fmaf(a3, w1.y, acc[3][5]);
            acc[3][6] = fmaf(a3, w1.z, acc[3][6]); acc[3][7] = fmaf(a3, w1.w, acc[3][7]);
        }
    }

    // ---- epilogue: bias + relu (+ ns pre-scale for next layer's gather)
    float4 bv0 = ((const float4*)bias)[cg * 2];
    float4 bv1 = ((const float4*)bias)[cg * 2 + 1];
    #pragma unroll
    for (int i = 0; i < 4; i++) {
        int row = row0 + rg * 4 + i;
        if (row < N_NODES) {
            float4 o0, o1;
            o0.x = fmaxf(acc[i][0] + bv0.x, 0.f);
            o0.y = fmaxf(acc[i][1] + bv0.y, 0.f);
            o0.z = fmaxf(acc[i][2] + bv0.z, 0.f);
            o0.w = fmaxf(acc[i][3] + bv0.w, 0.f);
            o1.x = fmaxf(acc[i][4] + bv1.x, 0.f);
            o1.y = fmaxf(acc[i][5] + bv1.y, 0.f);
            o1.z = fmaxf(acc[i][6] + bv1.z, 0.f);
            o1.w = fmaxf(acc[i][7] + bv1.w, 0.f);
            if (SCALE_OUT) {
                float s = ns[row];
                o0.x *= s; o0.y *= s; o0.z *= s; o0.w *= s;
                o1.x *= s; o1.y *= s; o1.z *= s; o1.w *= s;
            }
            ((float4*)out)[row * 32 + cg * 2] = o0;
            ((float4*)out)[row * 32 + cg * 2 + 1] = o1;
        }
    }
}

// ---------------------------------------------------------------------------
// 7) Fused projection + readout (segmented wave-scan over sorted graph_ids)
// ---------------------------------------------------------------------------
__global__ __launch_bounds__(256) void proj_readout_k(const float* __restrict__ h,
                                                      const int* __restrict__ gid,
                                                      const float* __restrict__ Wm,
                                                      float* __restrict__ hgp,
                                                      int* __restrict__ gcnt) {
    __shared__ float Wmt[10 * 144];
    int tid = threadIdx.x;
    for (int i = tid; i < 1280; i += 256) {
        int k = i / 10, o = i % 10;
        Wmt[o * 144 + k + 4 * (k >> 5)] = Wm[i];
    }
    __syncthreads();

    int v = blockIdx.x * 64 + (tid >> 2);
    int quarter = tid & 3;
    int lane = tid & 63;

    float acc[D_OUT];
    #pragma unroll
    for (int o = 0; o < D_OUT; o++) acc[o] = 0.f;
    int g = -1;
    int cnt = 0;
    if (v < N_NODES) {
        g = gid[v];
        cnt = (quarter == 0) ? 1 : 0;
        const float4* h4 = (const float4*)h + v * 32 + quarter * 8;
        const float* wbase = Wmt + quarter * 36;
        #pragma unroll
        for (int kk = 0; kk < 8; kk++) {
            float4 hv = h4[kk];
            #pragma unroll
            for (int o = 0; o < D_OUT; o++) {
                float4 w = *(const float4*)(wbase + o * 144 + kk * 4);
                acc[o] += hv.x * w.x + hv.y * w.y + hv.z * w.z + hv.w * w.w;
            }
        }
    }

    #pragma unroll
    for (int d = 1; d < 64; d <<= 1) {
        int gp = __shfl_up(g, d, 64);
        int cp = __shfl_up(cnt, d, 64);
        bool take = (lane >= d) && (gp == g);
        #pragma unroll
        for (int o = 0; o < D_OUT; o++) {
            float ap = __shfl_up(acc[o], d, 64);
            if (take) acc[o] += ap;
        }
        if (take) cnt += cp;
    }
    int gn = __shfl_down(g, 1, 64);
    bool tail = (lane == 63) || (gn != g);
    if (tail && g >= 0) {
        #pragma unroll
        for (int o = 0; o < D_OUT; o++) atomicAdd(&hgp[g * D_OUT + o], acc[o]);
        if (cnt > 0) atomicAdd(&gcnt[g], cnt);
    }
}

// ---------------------------------------------------------------------------
// 8) Final: logits = hgp/cnt + bm ; log_softmax over axis 0 (graphs)
// ---------------------------------------------------------------------------
__global__ __launch_bounds__(512) void final_k(const float* __restrict__ hgp,
                                               const int* __restrict__ gcnt,
                                               const float* __restrict__ bm,
                                               float* __restrict__ out) {
    __shared__ float lg[N_GRAPHS * D_OUT];
    __shared__ float colm[D_OUT], colls[D_OUT];
    int tid = threadIdx.x;
    if (tid < N_GRAPHS * D_OUT) {
        int g = tid / D_OUT, o = tid % D_OUT;
        float c = (float)gcnt[g];
        lg[tid] = hgp[tid] / (c > 1.f ? c : 1.f) + bm[o];
    }
    __syncthreads();
    if (tid < D_OUT) {
        float m = -1e30f;
        for (int g = 0; g < N_GRAPHS; g++) m = fmaxf(m, lg[g * D_OUT + tid]);
        float s = 0.f;
        for (int g = 0; g < N_GRAPHS; g++) s += expf(lg[g * D_OUT + tid] - m);
        colm[tid] = m; colls[tid] = logf(s);
    }
    __syncthreads();
    if (tid < N_GRAPHS * D_OUT) {
        int o = tid % D_OUT;
        out[tid] = lg[tid] - colm[o] - colls[o];
    }
}

// ---------------------------------------------------------------------------
// Launch
// ---------------------------------------------------------------------------
extern "C" void kernel_launch(void* const* d_in, const int* in_sizes, int n_in,
                              void* d_out, int out_size, void* d_ws, size_t ws_size,
                              hipStream_t stream) {
    const float* h_in = (const float*)d_in[0];
    const int*   src  = (const int*)d_in[1];
    const int*   dst  = (const int*)d_in[2];
    const int*   gid  = (const int*)d_in[3];
    const float* W1 = (const float*)d_in[4];  const float* b1 = (const float*)d_in[5];
    const float* W2 = (const float*)d_in[6];  const float* b2 = (const float*)d_in[7];
    const float* W3 = (const float*)d_in[8];  const float* b3 = (const float*)d_in[9];
    const float* Wm = (const float*)d_in[10]; const float* bm = (const float*)d_in[11];

    char* ws = (char*)d_ws;
    int*   cnt     = (int*)(ws + 0);          // 50000 ints; becomes scatter cursor
    int*   cnt_src = (int*)(ws + 200000);     // 50000 ints
    int*   gcnt    = (int*)(ws + 400000);     // 64 ints
    float* hgp     = (float*)(ws + 400256);   // 512 floats
    // zero region = [0, 402304)
    int*   row_ptr = (int*)(ws + 402304);     // 50001 ints (pad 50004)
    int*   col     = (int*)(ws + 602320);     // 800000 ints
    float* ns      = (float*)(ws + 3802320);  // 50000 floats
    float* nd      = (float*)(ws + 4002320);  // 50000 floats
    float* buf0    = (float*)(ws + 4202320);  // 6.4M floats
    float* buf1    = (float*)(ws + 29802320); // 6.4M floats
    // total: 55,402,320 bytes

    hipMemsetAsync(ws, 0, 402304, stream);

    hist_edges<<<3125, 256, 0, stream>>>(src, dst, cnt, cnt_src);
    scan_k<<<1, 1024, 0, stream>>>(cnt, row_ptr);
    norms_k<<<196, 256, 0, stream>>>(cnt_src, row_ptr, ns, nd);
    scatter_k<<<3125, 256, 0, stream>>>(src, dst, cnt, col);
    scale_k<<<6250, 256, 0, stream>>>(h_in, ns, buf1);   // buf1 = ns ∘ h

    // L1: buf1 -> buf0 (epilogue pre-scales by ns for L2's gather)
    fused_layer_k<true ><<<782, 256, 0, stream>>>(buf1, row_ptr, col, ns, nd, W1, b1, buf0);
    // L2: buf0 -> buf1 (pre-scaled for L3)
    fused_layer_k<true ><<<782, 256, 0, stream>>>(buf0, row_ptr, col, ns, nd, W2, b2, buf1);
    // L3: buf1 -> buf0 (unscaled output for readout)
    fused_layer_k<false><<<782, 256, 0, stream>>>(buf1, row_ptr, col, ns, nd, W3, b3, buf0);

    proj_readout_k<<<782, 256, 0, stream>>>(buf0, gid, Wm, hgp, gcnt);
    final_k<<<1, 512, 0, stream>>>(hgp, gcnt, bm, (float*)d_out);
}